// Round 9
// baseline (549.253 us; speedup 1.0000x reference)
//
#include <hip/hip_runtime.h>
#include <hip/hip_bf16.h>

#define NN 50000
#define EE 400000
#define TE (EE + NN)
#define SCAN_B ((NN + 255) / 256)   // 196 blocks

typedef float f4 __attribute__((ext_vector_type(4)));
typedef __bf16 b8 __attribute__((ext_vector_type(8)));

__device__ __forceinline__ float b2f(unsigned short u) {
    union { unsigned int i; float f; } c; c.i = ((unsigned int)u) << 16; return c.f;
}
__device__ __forceinline__ unsigned short f2b(float x) {
    union { unsigned int i; float f; } c; c.f = x;
    unsigned int i = c.i;
    return (unsigned short)((i + 0x7FFFu + ((i >> 16) & 1u)) >> 16);
}
__device__ __forceinline__ int clampi(int v, int lo, int hi) {
    return v < lo ? lo : (v > hi ? hi : v);
}

// ---- params block layout (ushort offsets, compile-time) ----
#define PO_WT    0                      // 3 x 65536 transposed W
#define PO_ATT   196608                 // 3 x (asrc 256 | adst 256 | bias 256)
#define PO_BT    198912                 // packed [cW1|pW1]^T  128x256
#define PO_BIAS  231680                 // packed [cb1|pb1]    128
#define PO_PW2   231808                 // 64x64
#define PO_PB2   235904                 // 64
#define PO_CW2   235968                 // 64x16
#define PO_CB2   236992                 // 16
#define PO_BT2   237008                 // heads GEMM B^T: 128 cols x 128 K (zero-padded)
#define PO_BIAS2 253392                 // heads bias: [cb2|pb2|0...]  128
#define PO_TOTAL 253520

// ---------------- dtype probes ----------------
__global__ void detect_kernel(const int* __restrict__ ei, const unsigned int* __restrict__ xw,
                              int* __restrict__ flag) {
    if (blockIdx.x != 0 || threadIdx.x != 0) return;
    int is64 = 1;
    for (int i = 0; i < 16; i++)
        if (ei[2 * i + 1] != 0) is64 = 0;
    flag[0] = is64;
    int cnt = 0;
    for (int i = 0; i < 256; i++) {
        unsigned short lo = (unsigned short)(xw[i] & 0xFFFFu);
        int e = (lo >> 7) & 0xFF;
        if (e >= 120 && e <= 132) cnt++;
    }
    flag[1] = (cnt >= 128) ? 1 : 0;
}

// ---------------- x convert, 4 elems/thread ----------------
__global__ __launch_bounds__(256) void convx_kernel(const void* __restrict__ src,
                                                    unsigned short* __restrict__ dst,
                                                    const int* __restrict__ flag) {
    int i = blockIdx.x * 256 + threadIdx.x;
    if (i >= NN * 256 / 4) return;
    if (flag[1]) {
        ((ushort4*)dst)[i] = ((const ushort4*)src)[i];
    } else {
        float4 v = ((const float4*)src)[i];
        ushort4 o; o.x = f2b(v.x); o.y = f2b(v.y); o.z = f2b(v.z); o.w = f2b(v.w);
        ((ushort4*)dst)[i] = o;
    }
}

// ---------------- fused weight prep ----------------
__device__ __forceinline__ float ldf(const void* p, int i, int bf) {
    return bf ? b2f(((const unsigned short*)p)[i]) : ((const float*)p)[i];
}
__global__ __launch_bounds__(256) void prep_kernel(
    const void* W1, const void* W2, const void* W3,
    const void* as1, const void* ad1, const void* b1,
    const void* as2, const void* ad2, const void* b2,
    const void* as3, const void* ad3, const void* b3,
    const void* pW1, const void* pb1, const void* pW2, const void* pb2,
    const void* cW1, const void* cb1, const void* cW2, const void* cb2,
    unsigned short* __restrict__ P, const int* __restrict__ flag) {
    int idx = blockIdx.x * 256 + threadIdx.x;
    if (idx >= PO_TOTAL) return;
    int bf = flag[1];
    float v;
    if (idx < PO_ATT) {
        int l = idx / 65536, r = idx % 65536;
        int n = r >> 8, k = r & 255;
        const void* W = (l == 0) ? W1 : (l == 1) ? W2 : W3;
        v = ldf(W, k * 256 + n, bf);
    } else if (idx < PO_BT) {
        int r = idx - PO_ATT;
        int l = r / 768, w = r % 768, which = w >> 8, j = w & 255;
        const void* s;
        if (which == 0) s = (l == 0) ? as1 : (l == 1) ? as2 : as3;
        else if (which == 1) s = (l == 0) ? ad1 : (l == 1) ? ad2 : ad3;
        else s = (l == 0) ? b1 : (l == 1) ? b2 : b3;
        v = ldf(s, j, bf);
    } else if (idx < PO_BIAS) {
        int r3 = idx - PO_BT;
        int r = r3 >> 8, k = r3 & 255;
        v = (r < 64) ? ldf(cW1, k * 64 + r, bf) : ldf(pW1, k * 64 + (r - 64), bf);
    } else if (idx < PO_PW2) {
        int r = idx - PO_BIAS;
        v = (r < 64) ? ldf(cb1, r, bf) : ldf(pb1, r - 64, bf);
    } else if (idx < PO_PB2) {
        v = ldf(pW2, idx - PO_PW2, bf);
    } else if (idx < PO_CW2) {
        v = ldf(pb2, idx - PO_PB2, bf);
    } else if (idx < PO_CB2) {
        v = ldf(cW2, idx - PO_CW2, bf);
    } else if (idx < PO_BT2) {
        v = ldf(cb2, idx - PO_CB2, bf);
    } else if (idx < PO_BIAS2) {
        int r2 = idx - PO_BT2;
        int r = r2 >> 7, k = r2 & 127;
        if (r < 16) v = (k < 64) ? ldf(cW2, k * 16 + r, bf) : 0.f;
        else if (r < 80) v = (k >= 64) ? ldf(pW2, (k - 64) * 64 + (r - 16), bf) : 0.f;
        else v = 0.f;
    } else {
        int r = idx - PO_BIAS2;
        v = (r < 16) ? ldf(cb2, r, bf) : (r < 80 ? ldf(pb2, r - 16, bf) : 0.f);
    }
    P[idx] = f2b(v);
}

__device__ __forceinline__ void edge_decode(const int* __restrict__ ei, int mode64, int e,
                                            int& src, int& dst) {
    if (e < EE) {
        if (mode64) { src = ei[2 * e]; dst = ei[2 * EE + 2 * e]; }
        else        { src = ei[e];     dst = ei[EE + e]; }
        src = clampi(src, 0, NN - 1);
        dst = clampi(dst, 0, NN - 1);
    } else {
        src = dst = e - EE;   // self-loop
    }
}

// ---------------- CSR build ----------------
__global__ void deg_kernel(const int* __restrict__ ei, const int* __restrict__ flag,
                           int* __restrict__ deg) {
    int e = blockIdx.x * 256 + threadIdx.x;
    if (e >= TE) return;
    int src, dst;
    edge_decode(ei, flag[0], e, src, dst);
    atomicAdd(&deg[dst], 1);
}

__global__ __launch_bounds__(256) void scanA_kernel(const int* __restrict__ deg,
                                                    int* __restrict__ offs, int* __restrict__ bsum) {
    __shared__ int s[256];
    int t = threadIdx.x, i = blockIdx.x * 256 + t;
    int v = (i < NN) ? deg[i] : 0;
    s[t] = v;
    __syncthreads();
    for (int off = 1; off < 256; off <<= 1) {
        int x = (t >= off) ? s[t - off] : 0;
        __syncthreads();
        s[t] += x;
        __syncthreads();
    }
    if (i < NN) offs[i] = s[t] - v;
    if (t == 255) bsum[blockIdx.x] = s[255];
}
__global__ __launch_bounds__(256) void scanB_kernel(int* __restrict__ bsum) {
    __shared__ int s[256];
    int t = threadIdx.x;
    int v = (t < SCAN_B) ? bsum[t] : 0;
    s[t] = v;
    __syncthreads();
    for (int off = 1; off < 256; off <<= 1) {
        int x = (t >= off) ? s[t - off] : 0;
        __syncthreads();
        s[t] += x;
        __syncthreads();
    }
    if (t < SCAN_B) bsum[t] = s[t] - v;
}
__global__ __launch_bounds__(256) void scanC_kernel(int* __restrict__ offs,
                                                    const int* __restrict__ bsum) {
    int t = threadIdx.x, i = blockIdx.x * 256 + t;
    if (i < NN) offs[i] += bsum[blockIdx.x];
    if (i == 0) offs[NN] = TE;
}

__global__ void scatter_kernel(const int* __restrict__ ei, const int* __restrict__ flag,
                               const int* __restrict__ offs,
                               int* __restrict__ cursor, int* __restrict__ srcs) {
    int e = blockIdx.x * 256 + threadIdx.x;
    if (e >= TE) return;
    int src, dst;
    edge_decode(ei, flag[0], e, src, dst);
    int pos = atomicAdd(&cursor[dst], 1);
    int slot = offs[dst] + pos;
    if (slot >= 0 && slot < TE) srcs[slot] = src;
}

// ---------------- MFMA GEMM: C[M,Nc] = A[M,K] @ Bt[Nc,K]^T, bf16 in, bf16/f32 out ----------------
__global__ __launch_bounds__(256) void gemm_bt_kernel(
    const unsigned short* __restrict__ A, const unsigned short* __restrict__ Bt,
    unsigned short* __restrict__ C, int M, int Nc, int K,
    const unsigned short* __restrict__ bias, int relu, int outf32) {
    __shared__ unsigned short As[128 * 40];
    __shared__ unsigned short Bs[128 * 40];
    int tid = threadIdx.x;
    int lane = tid & 63;
    int wave = tid >> 6;
    int wr = wave >> 1, wc = wave & 1;
    int m0 = blockIdx.x * 128;
    int n0 = blockIdx.y * 128;
    f4 acc[4][4];
#pragma unroll
    for (int i = 0; i < 4; i++)
#pragma unroll
        for (int j = 0; j < 4; j++) acc[i][j] = (f4){0.f, 0.f, 0.f, 0.f};

    int ar = tid >> 2;
    int ac = (tid & 3) << 3;
    for (int kt = 0; kt < K; kt += 32) {
#pragma unroll
        for (int h = 0; h < 2; h++) {
            int row = ar + h * 64;
            int gm = m0 + row;
            uint4 va = make_uint4(0u, 0u, 0u, 0u);
            if (gm < M) va = *(const uint4*)(A + (size_t)gm * K + kt + ac);
            *(uint4*)(&As[row * 40 + ac]) = va;
            int gn = n0 + row;
            uint4 vb = *(const uint4*)(Bt + (size_t)gn * K + kt + ac);
            *(uint4*)(&Bs[row * 40 + ac]) = vb;
        }
        __syncthreads();
        int kq = (lane >> 4) << 3;
        int rsel = lane & 15;
        b8 af[4], bfv[4];
#pragma unroll
        for (int i = 0; i < 4; i++) {
            af[i] = *(const b8*)(&As[(wr * 64 + i * 16 + rsel) * 40 + kq]);
            bfv[i] = *(const b8*)(&Bs[(wc * 64 + i * 16 + rsel) * 40 + kq]);
        }
#pragma unroll
        for (int i = 0; i < 4; i++)
#pragma unroll
            for (int j = 0; j < 4; j++)
                acc[i][j] = __builtin_amdgcn_mfma_f32_16x16x32_bf16(af[i], bfv[j], acc[i][j], 0, 0, 0);
        __syncthreads();
    }
    int cl = lane & 15, rq = lane >> 4;
#pragma unroll
    for (int j = 0; j < 4; j++) {
        int col = n0 + wc * 64 + j * 16 + cl;
        float bv = bias ? b2f(bias[col]) : 0.0f;
#pragma unroll
        for (int i = 0; i < 4; i++) {
#pragma unroll
            for (int r = 0; r < 4; r++) {
                int row = m0 + wr * 64 + i * 16 + rq * 4 + r;
                if (row < M) {
                    float v = acc[i][j][r] + bv;
                    if (relu) v = fmaxf(v, 0.0f);
                    if (outf32) ((float*)C)[(size_t)row * Nc + col] = v;
                    else C[(size_t)row * Nc + col] = f2b(v);
                }
            }
        }
    }
}

// ---------------- es/ed: per-node per-head attention dots ----------------
__global__ __launch_bounds__(256) void esed_kernel(
    const unsigned short* __restrict__ H, const unsigned short* __restrict__ asrc,
    const unsigned short* __restrict__ adst, float* __restrict__ es, float* __restrict__ ed, int N) {
    int gw = (blockIdx.x * 256 + threadIdx.x) >> 6;
    int lane = threadIdx.x & 63;
    if (gw >= N) return;
    int ch = lane << 2;
    int head = lane >> 4;
    int hc = (lane & 15) << 2;
    ushort4 hv = *(const ushort4*)(H + (size_t)gw * 256 + ch);
    ushort4 s4 = *(const ushort4*)(asrc + head * 64 + hc);
    ushort4 d4 = *(const ushort4*)(adst + head * 64 + hc);
    float h0 = b2f(hv.x), h1 = b2f(hv.y), h2 = b2f(hv.z), h3 = b2f(hv.w);
    float s = h0 * b2f(s4.x) + h1 * b2f(s4.y) + h2 * b2f(s4.z) + h3 * b2f(s4.w);
    float d = h0 * b2f(d4.x) + h1 * b2f(d4.y) + h2 * b2f(d4.z) + h3 * b2f(d4.w);
#pragma unroll
    for (int off = 1; off < 16; off <<= 1) {
        s += __shfl_xor(s, off, 64);
        d += __shfl_xor(d, off, 64);
    }
    if ((lane & 15) == 0) { es[gw * 4 + head] = s; ed[gw * 4 + head] = d; }
}

// ---------------- attention weights: wave per node, lanes over edges ----------------
// pass 1: shfl-reduced online max/sum per head; pass 2: write normalized w per edge.
__global__ __launch_bounds__(256) void attw_kernel(
    const float* __restrict__ es, const float* __restrict__ ed,
    const int* __restrict__ offs, const int* __restrict__ srcs,
    float* __restrict__ alpha, int N) {
    int gw = (blockIdx.x * 256 + threadIdx.x) >> 6;
    int lane = threadIdx.x & 63;
    if (gw >= N) return;
    int j0 = clampi(offs[gw], 0, TE);
    int j1 = clampi(offs[gw + 1], j0, TE);
    float4 edv = *(const float4*)(ed + gw * 4);
    float m0 = -1e30f, m1 = -1e30f, m2 = -1e30f, m3 = -1e30f;
    float s0 = 0.f, s1 = 0.f, s2 = 0.f, s3 = 0.f;
    for (int base = j0; base < j1; base += 64) {
        int j = base + lane;
        bool act = j < j1;
        int src = act ? clampi(srcs[j], 0, NN - 1) : 0;
        float4 ev = *(const float4*)(es + src * 4);
        float v0 = ev.x + edv.x; v0 = v0 > 0.f ? v0 : 0.2f * v0;
        float v1 = ev.y + edv.y; v1 = v1 > 0.f ? v1 : 0.2f * v1;
        float v2 = ev.z + edv.z; v2 = v2 > 0.f ? v2 : 0.2f * v2;
        float v3 = ev.w + edv.w; v3 = v3 > 0.f ? v3 : 0.2f * v3;
        if (!act) { v0 = v1 = v2 = v3 = -1e30f; }
        float c0 = v0, c1 = v1, c2 = v2, c3 = v3;
#pragma unroll
        for (int off = 1; off < 64; off <<= 1) {
            c0 = fmaxf(c0, __shfl_xor(c0, off, 64));
            c1 = fmaxf(c1, __shfl_xor(c1, off, 64));
            c2 = fmaxf(c2, __shfl_xor(c2, off, 64));
            c3 = fmaxf(c3, __shfl_xor(c3, off, 64));
        }
        float n0 = fmaxf(m0, c0), n1 = fmaxf(m1, c1), n2 = fmaxf(m2, c2), n3 = fmaxf(m3, c3);
        float e0 = act ? __expf(v0 - n0) : 0.f;
        float e1 = act ? __expf(v1 - n1) : 0.f;
        float e2 = act ? __expf(v2 - n2) : 0.f;
        float e3 = act ? __expf(v3 - n3) : 0.f;
#pragma unroll
        for (int off = 1; off < 64; off <<= 1) {
            e0 += __shfl_xor(e0, off, 64);
            e1 += __shfl_xor(e1, off, 64);
            e2 += __shfl_xor(e2, off, 64);
            e3 += __shfl_xor(e3, off, 64);
        }
        s0 = s0 * __expf(m0 - n0) + e0; m0 = n0;
        s1 = s1 * __expf(m1 - n1) + e1; m1 = n1;
        s2 = s2 * __expf(m2 - n2) + e2; m2 = n2;
        s3 = s3 * __expf(m3 - n3) + e3; m3 = n3;
    }
    float r0 = 1.f / (s0 + 1e-16f), r1 = 1.f / (s1 + 1e-16f);
    float r2 = 1.f / (s2 + 1e-16f), r3 = 1.f / (s3 + 1e-16f);
    for (int base = j0; base < j1; base += 64) {
        int j = base + lane;
        if (j < j1) {
            int src = clampi(srcs[j], 0, NN - 1);
            float4 ev = *(const float4*)(es + src * 4);   // L1-hot from pass 1
            float v0 = ev.x + edv.x; v0 = v0 > 0.f ? v0 : 0.2f * v0;
            float v1 = ev.y + edv.y; v1 = v1 > 0.f ? v1 : 0.2f * v1;
            float v2 = ev.z + edv.z; v2 = v2 > 0.f ? v2 : 0.2f * v2;
            float v3 = ev.w + edv.w; v3 = v3 > 0.f ? v3 : 0.2f * v3;
            float4 w = make_float4(__expf(v0 - m0) * r0, __expf(v1 - m1) * r1,
                                   __expf(v2 - m2) * r2, __expf(v3 - m3) * r3);
            *(float4*)(alpha + (size_t)j * 4) = w;
        }
    }
}

// ---------------- aggregation: wave per node, pure gather+FMA, unroll x8 ----------------
__global__ __launch_bounds__(256) void aggr_kernel(
    const unsigned short* __restrict__ H, const float* __restrict__ alpha,
    const int* __restrict__ offs, const int* __restrict__ srcs,
    const unsigned short* __restrict__ bias, unsigned short* __restrict__ out, int N, int elu) {
    int gw = (blockIdx.x * 256 + threadIdx.x) >> 6;
    int lane = threadIdx.x & 63;
    if (gw >= N) return;
    int ch = lane << 2;
    int head = lane >> 4;
    int j0 = clampi(offs[gw], 0, TE);
    int j1 = clampi(offs[gw + 1], j0, TE);
    float a0 = 0.f, a1 = 0.f, a2 = 0.f, a3 = 0.f;
    int j = j0;
    for (; j + 8 <= j1; j += 8) {
        int s[8]; float w[8]; ushort4 h[8];
#pragma unroll
        for (int u = 0; u < 8; u++) s[u] = clampi(srcs[j + u], 0, NN - 1);
#pragma unroll
        for (int u = 0; u < 8; u++) w[u] = alpha[(size_t)(j + u) * 4 + head];
#pragma unroll
        for (int u = 0; u < 8; u++) h[u] = *(const ushort4*)(H + (size_t)s[u] * 256 + ch);
#pragma unroll
        for (int u = 0; u < 8; u++) {
            a0 += w[u] * b2f(h[u].x); a1 += w[u] * b2f(h[u].y);
            a2 += w[u] * b2f(h[u].z); a3 += w[u] * b2f(h[u].w);
        }
    }
    for (; j < j1; j++) {
        int s0 = clampi(srcs[j], 0, NN - 1);
        float w0 = alpha[(size_t)j * 4 + head];
        ushort4 h0 = *(const ushort4*)(H + (size_t)s0 * 256 + ch);
        a0 += w0 * b2f(h0.x); a1 += w0 * b2f(h0.y);
        a2 += w0 * b2f(h0.z); a3 += w0 * b2f(h0.w);
    }
    ushort4 bv = *(const ushort4*)(bias + ch);
    a0 += b2f(bv.x); a1 += b2f(bv.y); a2 += b2f(bv.z); a3 += b2f(bv.w);
    if (elu) {
        a0 = a0 > 0.f ? a0 : __expf(a0) - 1.f;
        a1 = a1 > 0.f ? a1 : __expf(a1) - 1.f;
        a2 = a2 > 0.f ? a2 : __expf(a2) - 1.f;
        a3 = a3 > 0.f ? a3 : __expf(a3) - 1.f;
    }
    ushort4 o; o.x = f2b(a0); o.y = f2b(a1); o.z = f2b(a2); o.w = f2b(a3);
    *(ushort4*)(out + (size_t)gw * 256 + ch) = o;
}

// ---------------- finalize: log_softmax over 16 logits + proj copy, wave per node ----------------
__global__ __launch_bounds__(256) void finalize_kernel(
    const float* __restrict__ C2, float* __restrict__ out_logits,
    float* __restrict__ out_proj, int N) {
    int gw = (blockIdx.x * 256 + threadIdx.x) >> 6;
    int lane = threadIdx.x & 63;
    if (gw >= N) return;
    const float* row = C2 + (size_t)gw * 128;
    float lv = row[lane & 15];
    float mx = lv;
#pragma unroll
    for (int off = 1; off < 16; off <<= 1) mx = fmaxf(mx, __shfl_xor(mx, off, 64));
    float se = __expf(lv - mx);
#pragma unroll
    for (int off = 1; off < 16; off <<= 1) se += __shfl_xor(se, off, 64);
    float r = lv - mx - logf(se);
    if (lane < 16) out_logits[(size_t)gw * 16 + lane] = r;
    out_proj[(size_t)gw * 64 + lane] = row[16 + lane];
}

extern "C" void kernel_launch(void* const* d_in, const int* in_sizes, int n_in,
                              void* d_out, int out_size, void* d_ws, size_t ws_size,
                              hipStream_t stream) {
    (void)in_sizes; (void)n_in; (void)out_size; (void)ws_size;
    const int* ei = (const int*)d_in[1];

    char* p = (char*)d_ws;
    auto take = [&](size_t bytes) -> void* {
        void* r = (void*)p;
        p += (bytes + 255) & ~(size_t)255;
        return r;
    };
    int* flag   = (int*)take(256);
    int* deg    = (int*)take((size_t)NN * 4);
    int* cursor = (int*)take((size_t)NN * 4);
    int* offs   = (int*)take((size_t)(NN + 1) * 4);
    int* bsum   = (int*)take(256 * 4);
    int* srcs   = (int*)take((size_t)TE * 4);
    float* es   = (float*)take((size_t)NN * 16);
    float* ed   = (float*)take((size_t)NN * 16);
    float* alpha = (float*)take((size_t)TE * 16);
    unsigned short* bufH = (unsigned short*)take((size_t)NN * 256 * 2);
    unsigned short* buf1 = (unsigned short*)take((size_t)NN * 256 * 2);
    unsigned short* buf2 = (unsigned short*)take((size_t)NN * 256 * 2);
    unsigned short* P    = (unsigned short*)take((size_t)PO_TOTAL * 2);
    unsigned short* xb = buf2;      // x's bf16 copy; buf2 dead until layer-2 output
    unsigned short* tbuf = bufH;    // bufH dead after layer-3 aggregation
    float* C2 = (float*)buf1;       // buf1 dead after 4th GEMM; NN*128*4 == NN*256*2

    detect_kernel<<<1, 64, 0, stream>>>(ei, (const unsigned int*)d_in[0], flag);
    convx_kernel<<<NN * 256 / 4 / 256, 256, 0, stream>>>(d_in[0], xb, flag);
    prep_kernel<<<(PO_TOTAL + 255) / 256, 256, 0, stream>>>(
        d_in[2], d_in[6], d_in[10],
        d_in[3], d_in[4], d_in[5],
        d_in[7], d_in[8], d_in[9],
        d_in[11], d_in[12], d_in[13],
        d_in[14], d_in[15], d_in[16], d_in[17],
        d_in[18], d_in[19], d_in[20], d_in[21],
        P, flag);

    hipMemsetAsync(deg, 0, (size_t)NN * 4, stream);
    hipMemsetAsync(cursor, 0, (size_t)NN * 4, stream);
    deg_kernel<<<(TE + 255) / 256, 256, 0, stream>>>(ei, flag, deg);
    scanA_kernel<<<SCAN_B, 256, 0, stream>>>(deg, offs, bsum);
    scanB_kernel<<<1, 256, 0, stream>>>(bsum);
    scanC_kernel<<<SCAN_B, 256, 0, stream>>>(offs, bsum);
    scatter_kernel<<<(TE + 255) / 256, 256, 0, stream>>>(ei, flag, offs, cursor, srcs);

    const unsigned short* X = xb;
    unsigned short* outbuf[3] = {buf1, buf2, buf1};
    for (int l = 0; l < 3; l++) {
        const unsigned short* Wt  = P + PO_WT + l * 65536;
        const unsigned short* asr = P + PO_ATT + l * 768;
        const unsigned short* adr = P + PO_ATT + l * 768 + 256;
        const unsigned short* bcb = P + PO_ATT + l * 768 + 512;
        gemm_bt_kernel<<<dim3((NN + 127) / 128, 2), 256, 0, stream>>>(X, Wt, bufH, NN, 256, 256, nullptr, 0, 0);
        esed_kernel<<<12500, 256, 0, stream>>>(bufH, asr, adr, es, ed, NN);
        attw_kernel<<<12500, 256, 0, stream>>>(es, ed, offs, srcs, alpha, NN);
        aggr_kernel<<<12500, 256, 0, stream>>>(bufH, alpha, offs, srcs, bcb, outbuf[l], NN, (l < 2) ? 1 : 0);
        X = outbuf[l];
    }
    gemm_bt_kernel<<<dim3((NN + 127) / 128, 1), 256, 0, stream>>>(X, P + PO_BT, tbuf, NN, 128, 256, P + PO_BIAS, 1, 0);
    gemm_bt_kernel<<<dim3((NN + 127) / 128, 1), 256, 0, stream>>>(tbuf, P + PO_BT2, (unsigned short*)C2, NN, 128, 128, P + PO_BIAS2, 0, 1);
    float* out0 = (float*)d_out;
    float* out1 = out0 + (size_t)NN * 16;
    finalize_kernel<<<12500, 256, 0, stream>>>(C2, out0, out1, NN);
}

// Round 10
// 482.015 us; speedup vs baseline: 1.1395x; 1.1395x over previous
//
#include <hip/hip_runtime.h>
#include <hip/hip_bf16.h>

#define NN 50000
#define EE 400000
#define TE (EE + NN)
#define SCAN_B ((NN + 255) / 256)   // 196 blocks

typedef float f4 __attribute__((ext_vector_type(4)));
typedef __bf16 b8 __attribute__((ext_vector_type(8)));

__device__ __forceinline__ float b2f(unsigned short u) {
    union { unsigned int i; float f; } c; c.i = ((unsigned int)u) << 16; return c.f;
}
__device__ __forceinline__ unsigned short f2b(float x) {
    union { unsigned int i; float f; } c; c.f = x;
    unsigned int i = c.i;
    return (unsigned short)((i + 0x7FFFu + ((i >> 16) & 1u)) >> 16);
}
__device__ __forceinline__ int clampi(int v, int lo, int hi) {
    return v < lo ? lo : (v > hi ? hi : v);
}

// ---- params block layout (ushort offsets, compile-time) ----
#define PO_WT    0                      // 3 x 65536 transposed W
#define PO_ATT   196608                 // 3 x (asrc 256 | adst 256 | bias 256)
#define PO_BT    198912                 // packed [cW1|pW1]^T  128x256
#define PO_BIAS  231680                 // packed [cb1|pb1]    128
#define PO_PW2   231808                 // 64x64
#define PO_PB2   235904                 // 64
#define PO_CW2   235968                 // 64x16
#define PO_CB2   236992                 // 16
#define PO_BT2   237008                 // heads GEMM B^T: 128 cols x 128 K (zero-padded)
#define PO_BIAS2 253392                 // heads bias: [cb2|pb2|0...]  128
#define PO_TOTAL 253520

// ---------------- dtype probes ----------------
__global__ void detect_kernel(const int* __restrict__ ei, const unsigned int* __restrict__ xw,
                              int* __restrict__ flag) {
    if (blockIdx.x != 0 || threadIdx.x != 0) return;
    int is64 = 1;
    for (int i = 0; i < 16; i++)
        if (ei[2 * i + 1] != 0) is64 = 0;
    flag[0] = is64;
    int cnt = 0;
    for (int i = 0; i < 256; i++) {
        unsigned short lo = (unsigned short)(xw[i] & 0xFFFFu);
        int e = (lo >> 7) & 0xFF;
        if (e >= 120 && e <= 132) cnt++;
    }
    flag[1] = (cnt >= 128) ? 1 : 0;
}

// ---------------- x convert, 4 elems/thread ----------------
__global__ __launch_bounds__(256) void convx_kernel(const void* __restrict__ src,
                                                    unsigned short* __restrict__ dst,
                                                    const int* __restrict__ flag) {
    int i = blockIdx.x * 256 + threadIdx.x;
    if (i >= NN * 256 / 4) return;
    if (flag[1]) {
        ((ushort4*)dst)[i] = ((const ushort4*)src)[i];
    } else {
        float4 v = ((const float4*)src)[i];
        ushort4 o; o.x = f2b(v.x); o.y = f2b(v.y); o.z = f2b(v.z); o.w = f2b(v.w);
        ((ushort4*)dst)[i] = o;
    }
}

// ---------------- fused weight prep ----------------
__device__ __forceinline__ float ldf(const void* p, int i, int bf) {
    return bf ? b2f(((const unsigned short*)p)[i]) : ((const float*)p)[i];
}
__global__ __launch_bounds__(256) void prep_kernel(
    const void* W1, const void* W2, const void* W3,
    const void* as1, const void* ad1, const void* b1,
    const void* as2, const void* ad2, const void* b2,
    const void* as3, const void* ad3, const void* b3,
    const void* pW1, const void* pb1, const void* pW2, const void* pb2,
    const void* cW1, const void* cb1, const void* cW2, const void* cb2,
    unsigned short* __restrict__ P, const int* __restrict__ flag) {
    int idx = blockIdx.x * 256 + threadIdx.x;
    if (idx >= PO_TOTAL) return;
    int bf = flag[1];
    float v;
    if (idx < PO_ATT) {
        int l = idx / 65536, r = idx % 65536;
        int n = r >> 8, k = r & 255;
        const void* W = (l == 0) ? W1 : (l == 1) ? W2 : W3;
        v = ldf(W, k * 256 + n, bf);
    } else if (idx < PO_BT) {
        int r = idx - PO_ATT;
        int l = r / 768, w = r % 768, which = w >> 8, j = w & 255;
        const void* s;
        if (which == 0) s = (l == 0) ? as1 : (l == 1) ? as2 : as3;
        else if (which == 1) s = (l == 0) ? ad1 : (l == 1) ? ad2 : ad3;
        else s = (l == 0) ? b1 : (l == 1) ? b2 : b3;
        v = ldf(s, j, bf);
    } else if (idx < PO_BIAS) {
        int r3 = idx - PO_BT;
        int r = r3 >> 8, k = r3 & 255;
        v = (r < 64) ? ldf(cW1, k * 64 + r, bf) : ldf(pW1, k * 64 + (r - 64), bf);
    } else if (idx < PO_PW2) {
        int r = idx - PO_BIAS;
        v = (r < 64) ? ldf(cb1, r, bf) : ldf(pb1, r - 64, bf);
    } else if (idx < PO_PB2) {
        v = ldf(pW2, idx - PO_PW2, bf);
    } else if (idx < PO_CW2) {
        v = ldf(pb2, idx - PO_PB2, bf);
    } else if (idx < PO_CB2) {
        v = ldf(cW2, idx - PO_CW2, bf);
    } else if (idx < PO_BT2) {
        v = ldf(cb2, idx - PO_CB2, bf);
    } else if (idx < PO_BIAS2) {
        int r2 = idx - PO_BT2;
        int r = r2 >> 7, k = r2 & 127;
        if (r < 16) v = (k < 64) ? ldf(cW2, k * 16 + r, bf) : 0.f;
        else if (r < 80) v = (k >= 64) ? ldf(pW2, (k - 64) * 64 + (r - 16), bf) : 0.f;
        else v = 0.f;
    } else {
        int r = idx - PO_BIAS2;
        v = (r < 16) ? ldf(cb2, r, bf) : (r < 80 ? ldf(pb2, r - 16, bf) : 0.f);
    }
    P[idx] = f2b(v);
}

__device__ __forceinline__ void edge_decode(const int* __restrict__ ei, int mode64, int e,
                                            int& src, int& dst) {
    if (e < EE) {
        if (mode64) { src = ei[2 * e]; dst = ei[2 * EE + 2 * e]; }
        else        { src = ei[e];     dst = ei[EE + e]; }
        src = clampi(src, 0, NN - 1);
        dst = clampi(dst, 0, NN - 1);
    } else {
        src = dst = e - EE;   // self-loop
    }
}

// ---------------- CSR build ----------------
__global__ void deg_kernel(const int* __restrict__ ei, const int* __restrict__ flag,
                           int* __restrict__ deg) {
    int e = blockIdx.x * 256 + threadIdx.x;
    if (e >= TE) return;
    int src, dst;
    edge_decode(ei, flag[0], e, src, dst);
    atomicAdd(&deg[dst], 1);
}

__global__ __launch_bounds__(256) void scanA_kernel(const int* __restrict__ deg,
                                                    int* __restrict__ offs, int* __restrict__ bsum) {
    __shared__ int s[256];
    int t = threadIdx.x, i = blockIdx.x * 256 + t;
    int v = (i < NN) ? deg[i] : 0;
    s[t] = v;
    __syncthreads();
    for (int off = 1; off < 256; off <<= 1) {
        int x = (t >= off) ? s[t - off] : 0;
        __syncthreads();
        s[t] += x;
        __syncthreads();
    }
    if (i < NN) offs[i] = s[t] - v;
    if (t == 255) bsum[blockIdx.x] = s[255];
}
__global__ __launch_bounds__(256) void scanB_kernel(int* __restrict__ bsum) {
    __shared__ int s[256];
    int t = threadIdx.x;
    int v = (t < SCAN_B) ? bsum[t] : 0;
    s[t] = v;
    __syncthreads();
    for (int off = 1; off < 256; off <<= 1) {
        int x = (t >= off) ? s[t - off] : 0;
        __syncthreads();
        s[t] += x;
        __syncthreads();
    }
    if (t < SCAN_B) bsum[t] = s[t] - v;
}
__global__ __launch_bounds__(256) void scanC_kernel(int* __restrict__ offs,
                                                    const int* __restrict__ bsum) {
    int t = threadIdx.x, i = blockIdx.x * 256 + t;
    if (i < NN) offs[i] += bsum[blockIdx.x];
    if (i == 0) offs[NN] = TE;
}

__global__ void scatter_kernel(const int* __restrict__ ei, const int* __restrict__ flag,
                               const int* __restrict__ offs,
                               int* __restrict__ cursor, int* __restrict__ srcs) {
    int e = blockIdx.x * 256 + threadIdx.x;
    if (e >= TE) return;
    int src, dst;
    edge_decode(ei, flag[0], e, src, dst);
    int pos = atomicAdd(&cursor[dst], 1);
    int slot = offs[dst] + pos;
    if (slot >= 0 && slot < TE) srcs[slot] = src;
}

// ---------------- MFMA GEMM with global_load_lds staging ----------------
// C[M,Nc] = A[M,K] @ Bt[Nc,K]^T. LDS rows: 32 shorts (no pad) so the DMA's
// lane*16B layout matches. Quarter-swizzle slot = q ^ ((row>>1)&3) keeps the
// ds_read_b128 fragment reads at 2-way bank aliasing (free, m136).
__device__ __forceinline__ void async_ld16(const unsigned short* g, unsigned short* l) {
    __builtin_amdgcn_global_load_lds(
        (const __attribute__((address_space(1))) unsigned int*)g,
        (__attribute__((address_space(3))) unsigned int*)l, 16, 0, 0);
}

__global__ __launch_bounds__(256) void gemm_bt_kernel(
    const unsigned short* __restrict__ A, const unsigned short* __restrict__ Bt,
    unsigned short* __restrict__ C, int M, int Nc, int K,
    const unsigned short* __restrict__ bias, int relu, int outf32) {
    __shared__ unsigned short As[128 * 32];
    __shared__ unsigned short Bs[128 * 32];
    int tid = threadIdx.x;
    int lane = tid & 63;
    int wave = tid >> 6;
    int wr = wave >> 1, wc = wave & 1;
    int m0 = blockIdx.x * 128;
    int n0 = blockIdx.y * 128;
    f4 acc[4][4];
#pragma unroll
    for (int i = 0; i < 4; i++)
#pragma unroll
        for (int j = 0; j < 4; j++) acc[i][j] = (f4){0.f, 0.f, 0.f, 0.f};

    int rin = lane >> 2;                  // row within 16-row segment
    int qsl = lane & 3;                   // LDS quarter slot
    int qg  = qsl ^ ((rin >> 1) & 3);     // global quarter (swizzled)
    int rsel = lane & 15;
    int q16 = lane >> 4;
    int slotq = q16 ^ ((rsel >> 1) & 3);  // LDS slot holding global quarter q16

    for (int kt = 0; kt < K; kt += 32) {
#pragma unroll
        for (int t = 0; t < 4; t++) {
            int seg = wave * 4 + t;       // 0..15
            if (seg < 8) {
                int r = seg * 16 + rin;
                int gm = m0 + r;
                if (gm < M)
                    async_ld16(A + (size_t)gm * K + kt + qg * 8, &As[seg * 512]);
            } else {
                int r = (seg - 8) * 16 + rin;
                int gn = n0 + r;
                async_ld16(Bt + (size_t)gn * K + kt + qg * 8, &Bs[(seg - 8) * 512]);
            }
        }
        __syncthreads();
        b8 af[4], bfv[4];
#pragma unroll
        for (int i = 0; i < 4; i++) {
            af[i]  = *(const b8*)(&As[(wr * 64 + i * 16 + rsel) * 32 + slotq * 8]);
            bfv[i] = *(const b8*)(&Bs[(wc * 64 + i * 16 + rsel) * 32 + slotq * 8]);
        }
#pragma unroll
        for (int i = 0; i < 4; i++)
#pragma unroll
            for (int j = 0; j < 4; j++)
                acc[i][j] = __builtin_amdgcn_mfma_f32_16x16x32_bf16(af[i], bfv[j], acc[i][j], 0, 0, 0);
        __syncthreads();
    }
    int cl = lane & 15, rq = lane >> 4;
#pragma unroll
    for (int j = 0; j < 4; j++) {
        int col = n0 + wc * 64 + j * 16 + cl;
        float bv = bias ? b2f(bias[col]) : 0.0f;
#pragma unroll
        for (int i = 0; i < 4; i++) {
#pragma unroll
            for (int r = 0; r < 4; r++) {
                int row = m0 + wr * 64 + i * 16 + rq * 4 + r;
                if (row < M) {
                    float v = acc[i][j][r] + bv;
                    if (relu) v = fmaxf(v, 0.0f);
                    if (outf32) ((float*)C)[(size_t)row * Nc + col] = v;
                    else C[(size_t)row * Nc + col] = f2b(v);
                }
            }
        }
    }
}

// ---------------- es/ed: per-node per-head attention dots ----------------
__global__ __launch_bounds__(256) void esed_kernel(
    const unsigned short* __restrict__ H, const unsigned short* __restrict__ asrc,
    const unsigned short* __restrict__ adst, float* __restrict__ es, float* __restrict__ ed, int N) {
    int gw = (blockIdx.x * 256 + threadIdx.x) >> 6;
    int lane = threadIdx.x & 63;
    if (gw >= N) return;
    int ch = lane << 2;
    int head = lane >> 4;
    int hc = (lane & 15) << 2;
    ushort4 hv = *(const ushort4*)(H + (size_t)gw * 256 + ch);
    ushort4 s4 = *(const ushort4*)(asrc + head * 64 + hc);
    ushort4 d4 = *(const ushort4*)(adst + head * 64 + hc);
    float h0 = b2f(hv.x), h1 = b2f(hv.y), h2 = b2f(hv.z), h3 = b2f(hv.w);
    float s = h0 * b2f(s4.x) + h1 * b2f(s4.y) + h2 * b2f(s4.z) + h3 * b2f(s4.w);
    float d = h0 * b2f(d4.x) + h1 * b2f(d4.y) + h2 * b2f(d4.z) + h3 * b2f(d4.w);
#pragma unroll
    for (int off = 1; off < 16; off <<= 1) {
        s += __shfl_xor(s, off, 64);
        d += __shfl_xor(d, off, 64);
    }
    if ((lane & 15) == 0) { es[gw * 4 + head] = s; ed[gw * 4 + head] = d; }
}

// ---------------- online softmax stats per (dst, head): m and 1/s ----------------
__device__ __forceinline__ void online4(const float* __restrict__ es, int s,
                                        float e0, float e1, float e2, float e3,
                                        float& m0, float& m1, float& m2, float& m3,
                                        float& s0, float& s1, float& s2, float& s3) {
    float4 ev = *(const float4*)(es + s * 4);
    float v0 = ev.x + e0, v1 = ev.y + e1, v2 = ev.z + e2, v3 = ev.w + e3;
    v0 = v0 > 0.f ? v0 : 0.2f * v0; v1 = v1 > 0.f ? v1 : 0.2f * v1;
    v2 = v2 > 0.f ? v2 : 0.2f * v2; v3 = v3 > 0.f ? v3 : 0.2f * v3;
    float n0 = fmaxf(m0, v0), n1 = fmaxf(m1, v1), n2 = fmaxf(m2, v2), n3 = fmaxf(m3, v3);
    s0 = s0 * __expf(m0 - n0) + __expf(v0 - n0);
    s1 = s1 * __expf(m1 - n1) + __expf(v1 - n1);
    s2 = s2 * __expf(m2 - n2) + __expf(v2 - n2);
    s3 = s3 * __expf(m3 - n3) + __expf(v3 - n3);
    m0 = n0; m1 = n1; m2 = n2; m3 = n3;
}
__global__ void stats_kernel(const float* __restrict__ es, const float* __restrict__ ed,
                             const int* __restrict__ offs, const int* __restrict__ srcs,
                             float* __restrict__ mrs, int N) {
    int n = blockIdx.x * blockDim.x + threadIdx.x;
    if (n >= N) return;
    int j0 = clampi(offs[n], 0, TE);
    int j1 = clampi(offs[n + 1], j0, TE);
    float4 edv = *(const float4*)(ed + n * 4);
    float e0 = edv.x, e1 = edv.y, e2 = edv.z, e3 = edv.w;
    float m0 = -1e30f, m1 = -1e30f, m2 = -1e30f, m3 = -1e30f;
    float s0 = 0.f, s1 = 0.f, s2 = 0.f, s3 = 0.f;
    int j = j0;
    for (; j + 4 <= j1; j += 4) {
        int sa = clampi(srcs[j], 0, NN - 1), sb = clampi(srcs[j + 1], 0, NN - 1);
        int sc = clampi(srcs[j + 2], 0, NN - 1), sd = clampi(srcs[j + 3], 0, NN - 1);
        online4(es, sa, e0, e1, e2, e3, m0, m1, m2, m3, s0, s1, s2, s3);
        online4(es, sb, e0, e1, e2, e3, m0, m1, m2, m3, s0, s1, s2, s3);
        online4(es, sc, e0, e1, e2, e3, m0, m1, m2, m3, s0, s1, s2, s3);
        online4(es, sd, e0, e1, e2, e3, m0, m1, m2, m3, s0, s1, s2, s3);
    }
    for (; j < j1; j++) {
        int sa = clampi(srcs[j], 0, NN - 1);
        online4(es, sa, e0, e1, e2, e3, m0, m1, m2, m3, s0, s1, s2, s3);
    }
    float4 mv = make_float4(m0, m1, m2, m3);
    float4 rv = make_float4(1.f / (s0 + 1e-16f), 1.f / (s1 + 1e-16f),
                            1.f / (s2 + 1e-16f), 1.f / (s3 + 1e-16f));
    *(float4*)(mrs + n * 8) = mv;
    *(float4*)(mrs + n * 8 + 4) = rv;
}

// ---------------- aggregation: wave per node, recompute alpha inline, unroll x4 ----------------
__global__ __launch_bounds__(256) void aggr_kernel(
    const unsigned short* __restrict__ H, const float* __restrict__ es,
    const float* __restrict__ ed, const float* __restrict__ mrs,
    const int* __restrict__ offs, const int* __restrict__ srcs,
    const unsigned short* __restrict__ bias, unsigned short* __restrict__ out, int N, int elu) {
    int gw = (blockIdx.x * 256 + threadIdx.x) >> 6;
    int lane = threadIdx.x & 63;
    if (gw >= N) return;
    int ch = lane << 2;
    int head = lane >> 4;
    int j0 = clampi(offs[gw], 0, TE);
    int j1 = clampi(offs[gw + 1], j0, TE);
    float edh = ed[gw * 4 + head];
    float mh = mrs[gw * 8 + head];
    float rsh = mrs[gw * 8 + 4 + head];
    float a0 = 0.f, a1 = 0.f, a2 = 0.f, a3 = 0.f;
    int j = j0;
    for (; j + 4 <= j1; j += 4) {
        int s0 = clampi(srcs[j], 0, NN - 1), s1 = clampi(srcs[j + 1], 0, NN - 1);
        int s2 = clampi(srcs[j + 2], 0, NN - 1), s3 = clampi(srcs[j + 3], 0, NN - 1);
        float q0 = es[s0 * 4 + head], q1 = es[s1 * 4 + head];
        float q2 = es[s2 * 4 + head], q3 = es[s3 * 4 + head];
        ushort4 h0 = *(const ushort4*)(H + (size_t)s0 * 256 + ch);
        ushort4 h1 = *(const ushort4*)(H + (size_t)s1 * 256 + ch);
        ushort4 h2 = *(const ushort4*)(H + (size_t)s2 * 256 + ch);
        ushort4 h3 = *(const ushort4*)(H + (size_t)s3 * 256 + ch);
        float v0 = q0 + edh; v0 = v0 > 0.f ? v0 : 0.2f * v0;
        float v1 = q1 + edh; v1 = v1 > 0.f ? v1 : 0.2f * v1;
        float v2 = q2 + edh; v2 = v2 > 0.f ? v2 : 0.2f * v2;
        float v3 = q3 + edh; v3 = v3 > 0.f ? v3 : 0.2f * v3;
        float w0 = __expf(v0 - mh) * rsh, w1 = __expf(v1 - mh) * rsh;
        float w2 = __expf(v2 - mh) * rsh, w3 = __expf(v3 - mh) * rsh;
        a0 += w0 * b2f(h0.x) + w1 * b2f(h1.x) + w2 * b2f(h2.x) + w3 * b2f(h3.x);
        a1 += w0 * b2f(h0.y) + w1 * b2f(h1.y) + w2 * b2f(h2.y) + w3 * b2f(h3.y);
        a2 += w0 * b2f(h0.z) + w1 * b2f(h1.z) + w2 * b2f(h2.z) + w3 * b2f(h3.z);
        a3 += w0 * b2f(h0.w) + w1 * b2f(h1.w) + w2 * b2f(h2.w) + w3 * b2f(h3.w);
    }
    for (; j < j1; j++) {
        int s0 = clampi(srcs[j], 0, NN - 1);
        float q0 = es[s0 * 4 + head];
        ushort4 h0 = *(const ushort4*)(H + (size_t)s0 * 256 + ch);
        float v0 = q0 + edh; v0 = v0 > 0.f ? v0 : 0.2f * v0;
        float w0 = __expf(v0 - mh) * rsh;
        a0 += w0 * b2f(h0.x); a1 += w0 * b2f(h0.y);
        a2 += w0 * b2f(h0.z); a3 += w0 * b2f(h0.w);
    }
    ushort4 bv = *(const ushort4*)(bias + ch);
    a0 += b2f(bv.x); a1 += b2f(bv.y); a2 += b2f(bv.z); a3 += b2f(bv.w);
    if (elu) {
        a0 = a0 > 0.f ? a0 : __expf(a0) - 1.f;
        a1 = a1 > 0.f ? a1 : __expf(a1) - 1.f;
        a2 = a2 > 0.f ? a2 : __expf(a2) - 1.f;
        a3 = a3 > 0.f ? a3 : __expf(a3) - 1.f;
    }
    ushort4 o; o.x = f2b(a0); o.y = f2b(a1); o.z = f2b(a2); o.w = f2b(a3);
    *(ushort4*)(out + (size_t)gw * 256 + ch) = o;
}

// ---------------- finalize: log_softmax over 16 logits + proj copy, wave per node ----------------
__global__ __launch_bounds__(256) void finalize_kernel(
    const float* __restrict__ C2, float* __restrict__ out_logits,
    float* __restrict__ out_proj, int N) {
    int gw = (blockIdx.x * 256 + threadIdx.x) >> 6;
    int lane = threadIdx.x & 63;
    if (gw >= N) return;
    const float* row = C2 + (size_t)gw * 128;
    float lv = row[lane & 15];
    float mx = lv;
#pragma unroll
    for (int off = 1; off < 16; off <<= 1) mx = fmaxf(mx, __shfl_xor(mx, off, 64));
    float se = __expf(lv - mx);
#pragma unroll
    for (int off = 1; off < 16; off <<= 1) se += __shfl_xor(se, off, 64);
    float r = lv - mx - logf(se);
    if (lane < 16) out_logits[(size_t)gw * 16 + lane] = r;
    out_proj[(size_t)gw * 64 + lane] = row[16 + lane];
}

extern "C" void kernel_launch(void* const* d_in, const int* in_sizes, int n_in,
                              void* d_out, int out_size, void* d_ws, size_t ws_size,
                              hipStream_t stream) {
    (void)in_sizes; (void)n_in; (void)out_size; (void)ws_size;
    const int* ei = (const int*)d_in[1];

    char* p = (char*)d_ws;
    auto take = [&](size_t bytes) -> void* {
        void* r = (void*)p;
        p += (bytes + 255) & ~(size_t)255;
        return r;
    };
    int* flag   = (int*)take(256);
    int* deg    = (int*)take((size_t)NN * 4);
    int* cursor = (int*)take((size_t)NN * 4);
    int* offs   = (int*)take((size_t)(NN + 1) * 4);
    int* bsum   = (int*)take(256 * 4);
    int* srcs   = (int*)take((size_t)TE * 4);
    float* es   = (float*)take((size_t)NN * 16);
    float* ed   = (float*)take((size_t)NN * 16);
    float* mrs  = (float*)take((size_t)NN * 32);
    unsigned short* bufH = (unsigned short*)take((size_t)NN * 256 * 2);
    unsigned short* buf1 = (unsigned short*)take((size_t)NN * 256 * 2);
    unsigned short* buf2 = (unsigned short*)take((size_t)NN * 256 * 2);
    unsigned short* P    = (unsigned short*)take((size_t)PO_TOTAL * 2);
    unsigned short* xb = buf2;      // x's bf16 copy; buf2 dead until layer-2 output
    unsigned short* tbuf = bufH;    // bufH dead after layer-3 aggregation
    float* C2 = (float*)buf1;       // buf1 dead after 4th GEMM; NN*128*4 == NN*256*2

    detect_kernel<<<1, 64, 0, stream>>>(ei, (const unsigned int*)d_in[0], flag);
    convx_kernel<<<NN * 256 / 4 / 256, 256, 0, stream>>>(d_in[0], xb, flag);
    prep_kernel<<<(PO_TOTAL + 255) / 256, 256, 0, stream>>>(
        d_in[2], d_in[6], d_in[10],
        d_in[3], d_in[4], d_in[5],
        d_in[7], d_in[8], d_in[9],
        d_in[11], d_in[12], d_in[13],
        d_in[14], d_in[15], d_in[16], d_in[17],
        d_in[18], d_in[19], d_in[20], d_in[21],
        P, flag);

    hipMemsetAsync(deg, 0, (size_t)NN * 4, stream);
    hipMemsetAsync(cursor, 0, (size_t)NN * 4, stream);
    deg_kernel<<<(TE + 255) / 256, 256, 0, stream>>>(ei, flag, deg);
    scanA_kernel<<<SCAN_B, 256, 0, stream>>>(deg, offs, bsum);
    scanB_kernel<<<1, 256, 0, stream>>>(bsum);
    scanC_kernel<<<SCAN_B, 256, 0, stream>>>(offs, bsum);
    scatter_kernel<<<(TE + 255) / 256, 256, 0, stream>>>(ei, flag, offs, cursor, srcs);

    const unsigned short* X = xb;
    unsigned short* outbuf[3] = {buf1, buf2, buf1};
    for (int l = 0; l < 3; l++) {
        const unsigned short* Wt  = P + PO_WT + l * 65536;
        const unsigned short* asr = P + PO_ATT + l * 768;
        const unsigned short* adr = P + PO_ATT + l * 768 + 256;
        const unsigned short* bcb = P + PO_ATT + l * 768 + 512;
        gemm_bt_kernel<<<dim3((NN + 127) / 128, 2), 256, 0, stream>>>(X, Wt, bufH, NN, 256, 256, nullptr, 0, 0);
        esed_kernel<<<12500, 256, 0, stream>>>(bufH, asr, adr, es, ed, NN);
        stats_kernel<<<(NN + 255) / 256, 256, 0, stream>>>(es, ed, offs, srcs, mrs, NN);
        aggr_kernel<<<12500, 256, 0, stream>>>(bufH, es, ed, mrs, offs, srcs, bcb, outbuf[l], NN, (l < 2) ? 1 : 0);
        X = outbuf[l];
    }
    gemm_bt_kernel<<<dim3((NN + 127) / 128, 1), 256, 0, stream>>>(X, P + PO_BT, tbuf, NN, 128, 256, P + PO_BIAS, 1, 0);
    gemm_bt_kernel<<<dim3((NN + 127) / 128, 1), 256, 0, stream>>>(tbuf, P + PO_BT2, (unsigned short*)C2, NN, 128, 128, P + PO_BIAS2, 0, 1);
    float* out0 = (float*)d_out;
    float* out1 = out0 + (size_t)NN * 16;
    finalize_kernel<<<12500, 256, 0, stream>>>(C2, out0, out1, NN);
}